// Round 8
// baseline (163.360 us; speedup 1.0000x reference)
//
#include <hip/hip_runtime.h>
#include <hip/hip_bf16.h>

typedef __attribute__((ext_vector_type(8))) short short8;
typedef __attribute__((ext_vector_type(4))) float floatx4;

#define L2E 1.4426950408889634f

#if __has_builtin(__builtin_amdgcn_exp2f)
#define EXP2(x) __builtin_amdgcn_exp2f(x)
#else
#define EXP2(x) exp2f(x)
#endif
#if __has_builtin(__builtin_amdgcn_rcpf)
#define RCP(x) __builtin_amdgcn_rcpf(x)
#else
#define RCP(x) (1.0f / (x))
#endif

static __device__ __forceinline__ unsigned short f2bf(float f) {
    unsigned int u = __builtin_bit_cast(unsigned int, f);
    u += 0x7fffu + ((u >> 16) & 1u);   // RNE
    return (unsigned short)(u >> 16);
}
static __device__ __forceinline__ unsigned int pk_bf16(float a, float b) {
    __hip_bfloat162 h2 = __float22bfloat162_rn(make_float2(a, b));   // v_cvt_pk_bf16_f32
    unsigned int u;
    __builtin_memcpy(&u, &h2, 4);     // low16 = a, high16 = b
    return u;
}

// ---------------- 1) QKV GEMM, self-staging (unchanged) ----------------
__global__ __launch_bounds__(256) void k_qkv(const float* __restrict__ x,
                                             const float* __restrict__ qw,
                                             unsigned short* __restrict__ qm,
                                             unsigned short* __restrict__ km,
                                             unsigned short* __restrict__ vt) {
    __shared__ __align__(16) unsigned short At[64][136];
    __shared__ __align__(16) unsigned short Wt[64][136];
    const int tid = threadIdx.x;
    const int wave = tid >> 6, lane = tid & 63;
    const int l16 = lane & 15, quad = lane >> 4;
    const int m0 = blockIdx.x * 64;
    const int o0 = blockIdx.y * 64;

    floatx4 acc[4] = {};
    for (int rnd = 0; rnd < 2; ++rnd) {
        const int cbase = rnd * 128;
        if (rnd) __syncthreads();
        {
            const int moff = (tid & 3) * 16;
            #pragma unroll
            for (int half = 0; half < 2; ++half) {
                const int c_l = (tid >> 2) + 64 * half;
                const float4* xp = reinterpret_cast<const float4*>(
                    x + (size_t)(cbase + c_l) * 4096 + m0 + moff);
                const float4 f0 = xp[0], f1 = xp[1], f2 = xp[2], f3 = xp[3];
                At[moff +  0][c_l] = f2bf(f0.x); At[moff +  1][c_l] = f2bf(f0.y);
                At[moff +  2][c_l] = f2bf(f0.z); At[moff +  3][c_l] = f2bf(f0.w);
                At[moff +  4][c_l] = f2bf(f1.x); At[moff +  5][c_l] = f2bf(f1.y);
                At[moff +  6][c_l] = f2bf(f1.z); At[moff +  7][c_l] = f2bf(f1.w);
                At[moff +  8][c_l] = f2bf(f2.x); At[moff +  9][c_l] = f2bf(f2.y);
                At[moff + 10][c_l] = f2bf(f2.z); At[moff + 11][c_l] = f2bf(f2.w);
                At[moff + 12][c_l] = f2bf(f3.x); At[moff + 13][c_l] = f2bf(f3.y);
                At[moff + 14][c_l] = f2bf(f3.z); At[moff + 15][c_l] = f2bf(f3.w);
            }
        }
        {
            const int o_l = tid >> 2, cp = (tid & 3) * 32;
            const float4* wp = reinterpret_cast<const float4*>(
                qw + (size_t)(o0 + o_l) * 256 + cbase + cp);
            #pragma unroll
            for (int j = 0; j < 2; ++j) {
                const float4 g0 = wp[4 * j + 0], g1 = wp[4 * j + 1];
                const float4 g2 = wp[4 * j + 2], g3 = wp[4 * j + 3];
                unsigned int u[8];
                u[0] = pk_bf16(g0.x, g0.y); u[1] = pk_bf16(g0.z, g0.w);
                u[2] = pk_bf16(g1.x, g1.y); u[3] = pk_bf16(g1.z, g1.w);
                u[4] = pk_bf16(g2.x, g2.y); u[5] = pk_bf16(g2.z, g2.w);
                u[6] = pk_bf16(g3.x, g3.y); u[7] = pk_bf16(g3.z, g3.w);
                __builtin_memcpy(&Wt[o_l][cp + 16 * j], u, 32);
            }
        }
        __syncthreads();
        #pragma unroll
        for (int cc = 0; cc < 4; ++cc) {
            const int c0 = cc * 32 + quad * 8;
            const short8 a = *reinterpret_cast<const short8*>(&At[wave * 16 + l16][c0]);
            #pragma unroll
            for (int t4 = 0; t4 < 4; ++t4) {
                const short8 b = *reinterpret_cast<const short8*>(&Wt[t4 * 16 + l16][c0]);
                acc[t4] = __builtin_amdgcn_mfma_f32_16x16x32_bf16(a, b, acc[t4], 0, 0, 0);
            }
        }
    }
    const float qscale = 0.17677669529663687f * L2E;
    #pragma unroll
    for (int t4 = 0; t4 < 4; ++t4) {
        #pragma unroll
        for (int r = 0; r < 4; ++r) {
            const int n = m0 + wave * 16 + quad * 4 + r;
            const int o = o0 + t4 * 16 + l16;
            const int s = o >> 8, rem = o & 255, head = rem >> 5, t = rem & 31;
            if (s == 0)       qm[((size_t)head * 4096 + n) * 32 + t] = f2bf(acc[t4][r] * qscale);
            else if (s == 1)  km[((size_t)head * 4096 + n) * 32 + t] = f2bf(acc[t4][r]);
            else              vt[((size_t)head * 32 + t) * 4096 + n] = f2bf(acc[t4][r]);
        }
    }
}

// ---------------- 2) flash attention: LDS K/V, 2 tiles per barrier-phase, swizzled PT ----------------
// R23: bpermute transpose (R22) regressed vs R19's PT-LDS (82.9 vs 74.9us; 16
// bpermutes = MORE LDS-network ops than 8 ds_write + 4 ds_read; conflicts up).
// Reverted to the PT-LDS form and attacked the real structural costs of R19:
//  (1) one 64-key tile per __syncthreads -> ~1.7K cycles/phase for ~450cy of
//      serial chain: HALF the barriers by staging+computing TWO tiles per phase
//      (independent S->exp->PT->PV chains in separate PT slots + accumulators).
//  (2) PT stride-72 b128 reads were an 8-way bank conflict (bank = 4*(l16+quad)
//      mod 32): XOR-swizzle short-index ^((l16&7)<<3) on both write and read
//      takes it to ~2-way (free). 3.4M conflicts -> ~1M expected.
// Prefetch state = 4x(K,V) short8 = 32 VGPR; launch_bounds(256,2) caps at 128.
__global__ __launch_bounds__(256, 2) void k_attn(const unsigned short* __restrict__ qm,
                                                 const unsigned short* __restrict__ km,
                                                 const unsigned short* __restrict__ vt,
                                                 unsigned short* __restrict__ ao) {
    const int h   = blockIdx.y;
    const int nq0 = blockIdx.x * 64;          // 64 q-rows per block (same dq for all)
    const int tid = threadIdx.x;
    const int wv  = tid >> 6;                 // wave owns q-tile nq0 + wv*16
    const int lane = tid & 63;
    const int l16 = lane & 15, quad = lane >> 4;
    const int nqw = nq0 + wv * 16;

    __shared__ __align__(16) unsigned short Kt[2][2][2048];   // [buf][slot][key*32+dim ^ swz]
    __shared__ __align__(16) unsigned short Vt[2][2][2048];   // [buf][slot][kg*256+dim*8 ^ swz]
    __shared__ __align__(16) unsigned short PT[4][2][16][72]; // [wave][slot][q][key ^ swz]

    // B-operand for S^T: Q^T (q on l16, k=c on quad*8+j)
    const short8 a_q = *reinterpret_cast<const short8*>(
        qm + ((size_t)h * 4096 + nqw + l16) * 32 + quad * 8);

    const int hq = (nqw >> 4) & 15;           // per-wave h-coordinate
    const int dq = nq0 >> 8;                  // block-uniform d-coordinate
    float dw2[4];
    #pragma unroll
    for (int r = 0; r < 4; ++r) {
        const float dw = (float)(quad * 4 + r - l16);   // key_w - q_w
        dw2[r] = dw * dw;
    }

    const int dk_lo = (dq > 9) ? dq - 9 : 0;
    const int dk_hi = (dq < 6) ? dq + 9 : 15;
    const int NT = 4 * (dk_hi - dk_lo + 1);   // 40..64, divisible by 4

    // staging roles (256 threads move one 4KB K-tile + 4KB V-tile per slot)
    const int skey = tid >> 2;                // K: key 0..63
    const int sdo  = (tid & 3) * 8;           //    dim offset 0/8/16/24
    const int sdim = tid >> 3;                // V: dim 0..31
    const int skg  = tid & 7;                 //    keygroup 0..7
    const unsigned short* ksrc = km + ((size_t)h << 17) + skey * 32 + sdo;
    const unsigned short* vsrc = vt + (((size_t)h * 32 + sdim) << 12) + skg * 8;
    const int kdst = (skey * 32 + sdo) ^ ((skey & 7) << 3);
    const int vdst = (skg * 256 + sdim * 8) ^ (skg << 3);
    const int ptswz = (l16 & 7) << 3;         // PT short-index XOR (bits 3-5)

    float l_acc = 0.f;
    floatx4 o_acc[2][2] = {};                 // [slot][hf] -- independent chains

#define J0T(T) (((dk_lo + ((T) >> 2)) << 8) + (((T) & 3) << 6))

    // per-tile compute: S-MFMA -> exp/mask -> PT (swizzled) -> PV-MFMA
    auto comp = [&](int T, int cbuf, int sl) {
        const int dk = dk_lo + (T >> 2), g = T & 3;
        const int dd = dq - dk;
        const int bb = 100 - dd * dd;
        const int h0 = hq - 4 * g;
        int thr[4];
        thr[0] = bb - h0 * h0;
        thr[1] = bb - (h0 - 1) * (h0 - 1);
        thr[2] = bb - (h0 - 2) * (h0 - 2);
        thr[3] = bb - (h0 - 3) * (h0 - 3);
        if (!(thr[0] > 0 || thr[1] > 0 || thr[2] > 0 || thr[3] > 0)) return;

        #pragma unroll
        for (int t4 = 0; t4 < 4; ++t4) {
            const bool sib = (thr[t4 ^ 1] > 0);
            if (thr[t4] > 0) {
                const short8 kf = *reinterpret_cast<const short8*>(
                    &Kt[cbuf][sl][((t4 * 16 + l16) * 32 + quad * 8) ^ ((l16 & 7) << 3)]);
                const floatx4 sf = __builtin_amdgcn_mfma_f32_16x16x32_bf16(
                    kf, a_q, (floatx4){0.f, 0.f, 0.f, 0.f}, 0, 0, 0);
                const float thrf = (float)thr[t4];
                const float p0 = (dw2[0] < thrf) ? EXP2(sf[0]) : 0.f;
                const float p1 = (dw2[1] < thrf) ? EXP2(sf[1]) : 0.f;
                const float p2 = (dw2[2] < thrf) ? EXP2(sf[2]) : 0.f;
                const float p3 = (dw2[3] < thrf) ? EXP2(sf[3]) : 0.f;
                l_acc += (p0 + p1) + (p2 + p3);
                unsigned int pair[2];
                pair[0] = pk_bf16(p0, p1);
                pair[1] = pk_bf16(p2, p3);
                __builtin_memcpy(&PT[wv][sl][l16][(t4 * 16 + quad * 4) ^ ptswz], pair, 8);
            } else if (sib) {
                const unsigned int zz[2] = {0u, 0u};
                __builtin_memcpy(&PT[wv][sl][l16][(t4 * 16 + quad * 4) ^ ptswz], zz, 8);
            }
        }
        #pragma unroll
        for (int kt = 0; kt < 2; ++kt) {
            if (thr[2 * kt] > 0 || thr[2 * kt + 1] > 0) {
                const short8 b_p = *reinterpret_cast<const short8*>(
                    &PT[wv][sl][l16][(kt * 32 + quad * 8) ^ ptswz]);
                const int kg = kt * 4 + quad;
                #pragma unroll
                for (int hf = 0; hf < 2; ++hf) {
                    const short8 vf = *reinterpret_cast<const short8*>(
                        &Vt[cbuf][sl][(kg * 256 + (hf * 16 + l16) * 8) ^ (kg << 3)]);
                    o_acc[sl][hf] = __builtin_amdgcn_mfma_f32_16x16x32_bf16(
                        vf, b_p, o_acc[sl][hf], 0, 0, 0);
                }
            }
        }
    };

    // ---- prologue: tiles 0,1 -> buf0 slots 0,1; tiles 2,3 -> regs ----
    short8 gK0, gV0, gK1, gV1;
    {
        const int ja = J0T(0), jb = J0T(1);
        const short8 k0 = *reinterpret_cast<const short8*>(ksrc + (size_t)ja * 32);
        const short8 v0 = *reinterpret_cast<const short8*>(vsrc + ja);
        const short8 k1 = *reinterpret_cast<const short8*>(ksrc + (size_t)jb * 32);
        const short8 v1 = *reinterpret_cast<const short8*>(vsrc + jb);
        *reinterpret_cast<short8*>(&Kt[0][0][kdst]) = k0;
        *reinterpret_cast<short8*>(&Vt[0][0][vdst]) = v0;
        *reinterpret_cast<short8*>(&Kt[0][1][kdst]) = k1;
        *reinterpret_cast<short8*>(&Vt[0][1][vdst]) = v1;
        const int jc = J0T(2), jd = J0T(3);
        gK0 = *reinterpret_cast<const short8*>(ksrc + (size_t)jc * 32);
        gV0 = *reinterpret_cast<const short8*>(vsrc + jc);
        gK1 = *reinterpret_cast<const short8*>(ksrc + (size_t)jd * 32);
        gV1 = *reinterpret_cast<const short8*>(vsrc + jd);
    }
    __syncthreads();

    for (int t2 = 0; t2 < NT; t2 += 2) {
        const int cb = (t2 >> 1) & 1, nb = cb ^ 1;

        // (A) write prefetched tiles t2+2, t2+3 into the other buffer
        *reinterpret_cast<short8*>(&Kt[nb][0][kdst]) = gK0;
        *reinterpret_cast<short8*>(&Vt[nb][0][vdst]) = gV0;
        *reinterpret_cast<short8*>(&Kt[nb][1][kdst]) = gK1;
        *reinterpret_cast<short8*>(&Vt[nb][1][vdst]) = gV1;

        // (B) prefetch tiles t2+4, t2+5 (clamped)
        {
            int ta = t2 + 4; if (ta >= NT) ta = NT - 1;
            int tb = t2 + 5; if (tb >= NT) tb = NT - 1;
            const int ja = J0T(ta), jb = J0T(tb);
            gK0 = *reinterpret_cast<const short8*>(ksrc + (size_t)ja * 32);
            gV0 = *reinterpret_cast<const short8*>(vsrc + ja);
            gK1 = *reinterpret_cast<const short8*>(ksrc + (size_t)jb * 32);
            gV1 = *reinterpret_cast<const short8*>(vsrc + jb);
        }

        // (C) two independent tile chains per phase
        comp(t2, cb, 0);
        comp(t2 + 1, cb, 1);
        __syncthreads();
    }
#undef J0T

    // ---- epilogue: waves own disjoint q-rows; direct write ----
    l_acc += __shfl_xor(l_acc, 16);
    l_acc += __shfl_xor(l_acc, 32);
    const float inv = RCP(l_acc);
    #pragma unroll
    for (int hf = 0; hf < 2; ++hf) {
        const floatx4 os = o_acc[0][hf] + o_acc[1][hf];
        unsigned int uu[2];
        uu[0] = pk_bf16(os[0] * inv, os[1] * inv);
        uu[1] = pk_bf16(os[2] * inv, os[3] * inv);
        __builtin_memcpy(ao + (size_t)(nqw + l16) * 256 + h * 32 + hf * 16 + quad * 4,
                         uu, 8);
    }
}

// ---------------- 3) proj GEMM + bias, self-staging pw (unchanged) ----------------
__global__ __launch_bounds__(256) void k_proj(const unsigned short* __restrict__ ao,
                                              const float* __restrict__ pw,
                                              const float* __restrict__ pb,
                                              float* __restrict__ out) {
    __shared__ __align__(16) unsigned short Pt[64][264];
    const int tid = threadIdx.x;
    const int wave = tid >> 6, lane = tid & 63;
    const int l16 = lane & 15, quad = lane >> 4;
    const int n0 = blockIdx.x * 64;
    const int m0 = blockIdx.y * 64;

    {
        const int o_l = tid >> 2, cp = (tid & 3) * 64;
        const float4* wp = reinterpret_cast<const float4*>(pw + (size_t)(m0 + o_l) * 256 + cp);
        #pragma unroll
        for (int j = 0; j < 4; ++j) {
            const float4 g0 = wp[4 * j + 0], g1 = wp[4 * j + 1];
            const float4 g2 = wp[4 * j + 2], g3 = wp[4 * j + 3];
            unsigned int u[8];
            u[0] = pk_bf16(g0.x, g0.y); u[1] = pk_bf16(g0.z, g0.w);
            u[2] = pk_bf16(g1.x, g1.y); u[3] = pk_bf16(g1.z, g1.w);
            u[4] = pk_bf16(g2.x, g2.y); u[5] = pk_bf16(g2.z, g2.w);
            u[6] = pk_bf16(g3.x, g3.y); u[7] = pk_bf16(g3.z, g3.w);
            __builtin_memcpy(&Pt[o_l][cp + 16 * j], u, 32);
        }
    }
    __syncthreads();

    floatx4 acc[4] = {};
    #pragma unroll
    for (int cc = 0; cc < 8; ++cc) {
        const int c0 = cc * 32 + quad * 8;
        const short8 a = *reinterpret_cast<const short8*>(&Pt[wave * 16 + l16][c0]);
        #pragma unroll
        for (int t4 = 0; t4 < 4; ++t4) {
            const short8 b = *reinterpret_cast<const short8*>(
                ao + (size_t)(n0 + t4 * 16 + l16) * 256 + c0);
            acc[t4] = __builtin_amdgcn_mfma_f32_16x16x32_bf16(a, b, acc[t4], 0, 0, 0);
        }
    }
    #pragma unroll
    for (int t4 = 0; t4 < 4; ++t4) {
        #pragma unroll
        for (int r = 0; r < 4; ++r) {
            const int o = m0 + wave * 16 + quad * 4 + r;
            const int n = n0 + t4 * 16 + l16;
            out[(size_t)o * 4096 + n] = acc[t4][r] + pb[o];
        }
    }
}

extern "C" void kernel_launch(void* const* d_in, const int* in_sizes, int n_in,
                              void* d_out, int out_size, void* d_ws, size_t ws_size,
                              hipStream_t stream) {
    const float* x      = (const float*)d_in[0];
    const float* qkv_w  = (const float*)d_in[1];
    const float* proj_w = (const float*)d_in[2];
    const float* proj_b = (const float*)d_in[3];
    float* out = (float*)d_out;                    // [256,4096] fp32

    char* B = (char*)d_ws;
    const size_t MB = 1u << 20;
    unsigned short* ao = (unsigned short*)(B);
    unsigned short* qm = (unsigned short*)(B + 2 * MB);
    unsigned short* km = (unsigned short*)(B + 4 * MB);
    unsigned short* vt = (unsigned short*)(B + 6 * MB);

    k_qkv<<<dim3(64, 12), 256, 0, stream>>>(x, qkv_w, qm, km, vt);
    k_attn<<<dim3(64, 8), 256, 0, stream>>>(qm, km, vt, ao);
    k_proj<<<dim3(64, 4), 256, 0, stream>>>(ao, proj_w, proj_b, out);
}

// Round 9
// 154.312 us; speedup vs baseline: 1.0586x; 1.0586x over previous
//
#include <hip/hip_runtime.h>
#include <hip/hip_bf16.h>

typedef __attribute__((ext_vector_type(8))) short short8;
typedef __attribute__((ext_vector_type(4))) float floatx4;

#define L2E 1.4426950408889634f

#if __has_builtin(__builtin_amdgcn_exp2f)
#define EXP2(x) __builtin_amdgcn_exp2f(x)
#else
#define EXP2(x) exp2f(x)
#endif
#if __has_builtin(__builtin_amdgcn_rcpf)
#define RCP(x) __builtin_amdgcn_rcpf(x)
#else
#define RCP(x) (1.0f / (x))
#endif

static __device__ __forceinline__ unsigned short f2bf(float f) {
    unsigned int u = __builtin_bit_cast(unsigned int, f);
    u += 0x7fffu + ((u >> 16) & 1u);   // RNE
    return (unsigned short)(u >> 16);
}
static __device__ __forceinline__ unsigned int pk_bf16(float a, float b) {
    __hip_bfloat162 h2 = __float22bfloat162_rn(make_float2(a, b));   // v_cvt_pk_bf16_f32
    unsigned int u;
    __builtin_memcpy(&u, &h2, 4);     // low16 = a, high16 = b
    return u;
}

// ---------------- 1) QKV GEMM, self-staging (unchanged) ----------------
__global__ __launch_bounds__(256) void k_qkv(const float* __restrict__ x,
                                             const float* __restrict__ qw,
                                             unsigned short* __restrict__ qm,
                                             unsigned short* __restrict__ km,
                                             unsigned short* __restrict__ vt) {
    __shared__ __align__(16) unsigned short At[64][136];
    __shared__ __align__(16) unsigned short Wt[64][136];
    const int tid = threadIdx.x;
    const int wave = tid >> 6, lane = tid & 63;
    const int l16 = lane & 15, quad = lane >> 4;
    const int m0 = blockIdx.x * 64;
    const int o0 = blockIdx.y * 64;

    floatx4 acc[4] = {};
    for (int rnd = 0; rnd < 2; ++rnd) {
        const int cbase = rnd * 128;
        if (rnd) __syncthreads();
        {
            const int moff = (tid & 3) * 16;
            #pragma unroll
            for (int half = 0; half < 2; ++half) {
                const int c_l = (tid >> 2) + 64 * half;
                const float4* xp = reinterpret_cast<const float4*>(
                    x + (size_t)(cbase + c_l) * 4096 + m0 + moff);
                const float4 f0 = xp[0], f1 = xp[1], f2 = xp[2], f3 = xp[3];
                At[moff +  0][c_l] = f2bf(f0.x); At[moff +  1][c_l] = f2bf(f0.y);
                At[moff +  2][c_l] = f2bf(f0.z); At[moff +  3][c_l] = f2bf(f0.w);
                At[moff +  4][c_l] = f2bf(f1.x); At[moff +  5][c_l] = f2bf(f1.y);
                At[moff +  6][c_l] = f2bf(f1.z); At[moff +  7][c_l] = f2bf(f1.w);
                At[moff +  8][c_l] = f2bf(f2.x); At[moff +  9][c_l] = f2bf(f2.y);
                At[moff + 10][c_l] = f2bf(f2.z); At[moff + 11][c_l] = f2bf(f2.w);
                At[moff + 12][c_l] = f2bf(f3.x); At[moff + 13][c_l] = f2bf(f3.y);
                At[moff + 14][c_l] = f2bf(f3.z); At[moff + 15][c_l] = f2bf(f3.w);
            }
        }
        {
            const int o_l = tid >> 2, cp = (tid & 3) * 32;
            const float4* wp = reinterpret_cast<const float4*>(
                qw + (size_t)(o0 + o_l) * 256 + cbase + cp);
            #pragma unroll
            for (int j = 0; j < 2; ++j) {
                const float4 g0 = wp[4 * j + 0], g1 = wp[4 * j + 1];
                const float4 g2 = wp[4 * j + 2], g3 = wp[4 * j + 3];
                unsigned int u[8];
                u[0] = pk_bf16(g0.x, g0.y); u[1] = pk_bf16(g0.z, g0.w);
                u[2] = pk_bf16(g1.x, g1.y); u[3] = pk_bf16(g1.z, g1.w);
                u[4] = pk_bf16(g2.x, g2.y); u[5] = pk_bf16(g2.z, g2.w);
                u[6] = pk_bf16(g3.x, g3.y); u[7] = pk_bf16(g3.z, g3.w);
                __builtin_memcpy(&Wt[o_l][cp + 16 * j], u, 32);
            }
        }
        __syncthreads();
        #pragma unroll
        for (int cc = 0; cc < 4; ++cc) {
            const int c0 = cc * 32 + quad * 8;
            const short8 a = *reinterpret_cast<const short8*>(&At[wave * 16 + l16][c0]);
            #pragma unroll
            for (int t4 = 0; t4 < 4; ++t4) {
                const short8 b = *reinterpret_cast<const short8*>(&Wt[t4 * 16 + l16][c0]);
                acc[t4] = __builtin_amdgcn_mfma_f32_16x16x32_bf16(a, b, acc[t4], 0, 0, 0);
            }
        }
    }
    const float qscale = 0.17677669529663687f * L2E;
    #pragma unroll
    for (int t4 = 0; t4 < 4; ++t4) {
        #pragma unroll
        for (int r = 0; r < 4; ++r) {
            const int n = m0 + wave * 16 + quad * 4 + r;
            const int o = o0 + t4 * 16 + l16;
            const int s = o >> 8, rem = o & 255, head = rem >> 5, t = rem & 31;
            if (s == 0)       qm[((size_t)head * 4096 + n) * 32 + t] = f2bf(acc[t4][r] * qscale);
            else if (s == 1)  km[((size_t)head * 4096 + n) * 32 + t] = f2bf(acc[t4][r]);
            else              vt[((size_t)head * 32 + t) * 4096 + n] = f2bf(acc[t4][r]);
        }
    }
}

// ---------------- 2) flash attention: 32-q blocks (2 waves), LDS K/V, T14 stage split ----------------
// R24: R23's PT "swizzle" was mis-derived -- bank math shows it put 16/64 lanes in
// one 4-bank group (conflicts 3.4M->13.9M, 75->87us). Reverted PT to R19's plain
// layout (whose b128 read is already at the uniform 8/bank floor). The real
// remaining structure in R19: 2800 cy/phase vs ~720 cy/SIMD of issue (VALUBusy 26%
// -- matches exactly); the ~500-700cy serial chain runs in barrier lockstep with
// only TWO independent barrier groups per CU. This round: 32-q blocks (2 waves,
// 128 thr) -> grid 1024, FOUR independent 2-wave barrier groups per CU (same 8
// waves/CU) -> chains of different groups interleave; barriers sync 2 waves not 4;
// finer tail. Staging still LDS-shared (2 chunks/thread), T14 order: issue global
// loads at phase top, ds_write at phase end (vmcnt wait at the write, not the
// barrier), compute in between.
__global__ __launch_bounds__(128, 4) void k_attn(const unsigned short* __restrict__ qm,
                                                 const unsigned short* __restrict__ km,
                                                 const unsigned short* __restrict__ vt,
                                                 unsigned short* __restrict__ ao) {
    const int h   = blockIdx.y;
    const int nq0 = blockIdx.x * 32;          // 32 q-rows per block (same dq)
    const int tid = threadIdx.x;              // 0..127
    const int wv  = tid >> 6;                 // 0/1: wave owns q-tile nq0 + wv*16
    const int lane = tid & 63;
    const int l16 = lane & 15, quad = lane >> 4;
    const int nqw = nq0 + wv * 16;

    __shared__ __align__(16) unsigned short Kt[2][2048];   // [buf][key*32+dim ^ swz]
    __shared__ __align__(16) unsigned short Vt[2][2048];   // [buf][kg*256+dim*8 ^ swz]
    __shared__ __align__(16) unsigned short PT[2][16][72]; // [wave][q][key] (plain)

    // B-operand for S^T: Q^T (q on l16, k=c on quad*8+j)
    const short8 a_q = *reinterpret_cast<const short8*>(
        qm + ((size_t)h * 4096 + nqw + l16) * 32 + quad * 8);

    const int hq = (nqw >> 4) & 15;           // per-wave h-coordinate
    const int dq = nq0 >> 8;                  // block-uniform d-coordinate
    float dw2[4];
    #pragma unroll
    for (int r = 0; r < 4; ++r) {
        const float dw = (float)(quad * 4 + r - l16);   // key_w - q_w
        dw2[r] = dw * dw;
    }

    const int dk_lo = (dq > 9) ? dq - 9 : 0;
    const int dk_hi = (dq < 6) ? dq + 9 : 15;
    const int NT = 4 * (dk_hi - dk_lo + 1);   // 40..64 tiles

    // staging roles: 128 threads x 2 chunks cover one 4KB K-tile + 4KB V-tile.
    // K chunk A: key = tid>>2 (0..31), dim-off = (tid&3)*8; chunk B: key += 32.
    const int skey = tid >> 2, sdo = (tid & 3) * 8;
    const unsigned short* ksrcA = km + ((size_t)h << 17) + skey * 32 + sdo;
    const unsigned short* ksrcB = ksrcA + 32 * 32;
    const int kdA = (skey * 32 + sdo) ^ ((skey & 7) << 3);
    const int kdB = kdA + 1024;               // (key+32)&7 == key&7
    // V chunk A: kg = tid&7, dim = tid>>3 (0..15); chunk B: dim += 16.
    const int skg = tid & 7, sdim = tid >> 3;
    const unsigned short* vsrcA = vt + (((size_t)h * 32 + sdim) << 12) + skg * 8;
    const unsigned short* vsrcB = vsrcA + (16 << 12);
    const int vdA = (skg * 256 + sdim * 8) ^ (skg << 3);
    const int vdB = vdA + 128;

    float l_acc = 0.f;
    floatx4 o_acc[2] = {};

#define J0T(T) (((dk_lo + ((T) >> 2)) << 8) + (((T) & 3) << 6))

    // per-tile compute (R19 body, PT plain)
    auto comp = [&](int T, int cbuf) {
        const int dk = dk_lo + (T >> 2), g = T & 3;
        const int dd = dq - dk;
        const int bb = 100 - dd * dd;
        const int h0 = hq - 4 * g;
        int thr[4];
        thr[0] = bb - h0 * h0;
        thr[1] = bb - (h0 - 1) * (h0 - 1);
        thr[2] = bb - (h0 - 2) * (h0 - 2);
        thr[3] = bb - (h0 - 3) * (h0 - 3);
        if (!(thr[0] > 0 || thr[1] > 0 || thr[2] > 0 || thr[3] > 0)) return;

        #pragma unroll
        for (int t4 = 0; t4 < 4; ++t4) {
            const bool sib = (thr[t4 ^ 1] > 0);
            if (thr[t4] > 0) {
                const short8 kf = *reinterpret_cast<const short8*>(
                    &Kt[cbuf][((t4 * 16 + l16) * 32 + quad * 8) ^ ((l16 & 7) << 3)]);
                const floatx4 sf = __builtin_amdgcn_mfma_f32_16x16x32_bf16(
                    kf, a_q, (floatx4){0.f, 0.f, 0.f, 0.f}, 0, 0, 0);
                const float thrf = (float)thr[t4];
                const float p0 = (dw2[0] < thrf) ? EXP2(sf[0]) : 0.f;
                const float p1 = (dw2[1] < thrf) ? EXP2(sf[1]) : 0.f;
                const float p2 = (dw2[2] < thrf) ? EXP2(sf[2]) : 0.f;
                const float p3 = (dw2[3] < thrf) ? EXP2(sf[3]) : 0.f;
                l_acc += (p0 + p1) + (p2 + p3);
                unsigned int pair[2];
                pair[0] = pk_bf16(p0, p1);
                pair[1] = pk_bf16(p2, p3);
                __builtin_memcpy(&PT[wv][l16][t4 * 16 + quad * 4], pair, 8);
            } else if (sib) {
                const unsigned int zz[2] = {0u, 0u};
                __builtin_memcpy(&PT[wv][l16][t4 * 16 + quad * 4], zz, 8);
            }
        }
        #pragma unroll
        for (int kt = 0; kt < 2; ++kt) {
            if (thr[2 * kt] > 0 || thr[2 * kt + 1] > 0) {
                const short8 b_p = *reinterpret_cast<const short8*>(
                    &PT[wv][l16][kt * 32 + quad * 8]);
                const int kg = kt * 4 + quad;
                #pragma unroll
                for (int hf = 0; hf < 2; ++hf) {
                    const short8 vf = *reinterpret_cast<const short8*>(
                        &Vt[cbuf][(kg * 256 + (hf * 16 + l16) * 8) ^ (kg << 3)]);
                    o_acc[hf] = __builtin_amdgcn_mfma_f32_16x16x32_bf16(
                        vf, b_p, o_acc[hf], 0, 0, 0);
                }
            }
        }
    };

    short8 rK0, rK1, rV0, rV1;
#define LOADT(T) {                                                        \
        const int j0_ = J0T(T);                                           \
        rK0 = *reinterpret_cast<const short8*>(ksrcA + (size_t)j0_ * 32); \
        rK1 = *reinterpret_cast<const short8*>(ksrcB + (size_t)j0_ * 32); \
        rV0 = *reinterpret_cast<const short8*>(vsrcA + j0_);              \
        rV1 = *reinterpret_cast<const short8*>(vsrcB + j0_);              \
    }
#define WRITET(NB) {                                                      \
        *reinterpret_cast<short8*>(&Kt[NB][kdA]) = rK0;                   \
        *reinterpret_cast<short8*>(&Kt[NB][kdB]) = rK1;                   \
        *reinterpret_cast<short8*>(&Vt[NB][vdA]) = rV0;                   \
        *reinterpret_cast<short8*>(&Vt[NB][vdB]) = rV1;                   \
    }

    // prologue: tile 0 -> buf 0
    LOADT(0)
    WRITET(0)
    __syncthreads();

    for (int t = 0; t < NT; ++t) {
        const int cb = t & 1, nb = cb ^ 1;
        const int tn = (t + 1 < NT) ? t + 1 : t;
        LOADT(tn)            // issue next tile's global loads (latency hides under comp)
        comp(t, cb);         // compute current tile from resident buffer
        WRITET(nb)           // vmcnt wait lands here, then ds_write
        __syncthreads();
    }
#undef WRITET
#undef LOADT
#undef J0T

    // ---- epilogue: waves own disjoint q-rows; direct write ----
    l_acc += __shfl_xor(l_acc, 16);
    l_acc += __shfl_xor(l_acc, 32);
    const float inv = RCP(l_acc);
    #pragma unroll
    for (int hf = 0; hf < 2; ++hf) {
        unsigned int uu[2];
        uu[0] = pk_bf16(o_acc[hf][0] * inv, o_acc[hf][1] * inv);
        uu[1] = pk_bf16(o_acc[hf][2] * inv, o_acc[hf][3] * inv);
        __builtin_memcpy(ao + (size_t)(nqw + l16) * 256 + h * 32 + hf * 16 + quad * 4,
                         uu, 8);
    }
}

// ---------------- 3) proj GEMM + bias, self-staging pw (unchanged) ----------------
__global__ __launch_bounds__(256) void k_proj(const unsigned short* __restrict__ ao,
                                              const float* __restrict__ pw,
                                              const float* __restrict__ pb,
                                              float* __restrict__ out) {
    __shared__ __align__(16) unsigned short Pt[64][264];
    const int tid = threadIdx.x;
    const int wave = tid >> 6, lane = tid & 63;
    const int l16 = lane & 15, quad = lane >> 4;
    const int n0 = blockIdx.x * 64;
    const int m0 = blockIdx.y * 64;

    {
        const int o_l = tid >> 2, cp = (tid & 3) * 64;
        const float4* wp = reinterpret_cast<const float4*>(pw + (size_t)(m0 + o_l) * 256 + cp);
        #pragma unroll
        for (int j = 0; j < 4; ++j) {
            const float4 g0 = wp[4 * j + 0], g1 = wp[4 * j + 1];
            const float4 g2 = wp[4 * j + 2], g3 = wp[4 * j + 3];
            unsigned int u[8];
            u[0] = pk_bf16(g0.x, g0.y); u[1] = pk_bf16(g0.z, g0.w);
            u[2] = pk_bf16(g1.x, g1.y); u[3] = pk_bf16(g1.z, g1.w);
            u[4] = pk_bf16(g2.x, g2.y); u[5] = pk_bf16(g2.z, g2.w);
            u[6] = pk_bf16(g3.x, g3.y); u[7] = pk_bf16(g3.z, g3.w);
            __builtin_memcpy(&Pt[o_l][cp + 16 * j], u, 32);
        }
    }
    __syncthreads();

    floatx4 acc[4] = {};
    #pragma unroll
    for (int cc = 0; cc < 8; ++cc) {
        const int c0 = cc * 32 + quad * 8;
        const short8 a = *reinterpret_cast<const short8*>(&Pt[wave * 16 + l16][c0]);
        #pragma unroll
        for (int t4 = 0; t4 < 4; ++t4) {
            const short8 b = *reinterpret_cast<const short8*>(
                ao + (size_t)(n0 + t4 * 16 + l16) * 256 + c0);
            acc[t4] = __builtin_amdgcn_mfma_f32_16x16x32_bf16(a, b, acc[t4], 0, 0, 0);
        }
    }
    #pragma unroll
    for (int t4 = 0; t4 < 4; ++t4) {
        #pragma unroll
        for (int r = 0; r < 4; ++r) {
            const int o = m0 + wave * 16 + quad * 4 + r;
            const int n = n0 + t4 * 16 + l16;
            out[(size_t)o * 4096 + n] = acc[t4][r] + pb[o];
        }
    }
}

extern "C" void kernel_launch(void* const* d_in, const int* in_sizes, int n_in,
                              void* d_out, int out_size, void* d_ws, size_t ws_size,
                              hipStream_t stream) {
    const float* x      = (const float*)d_in[0];
    const float* qkv_w  = (const float*)d_in[1];
    const float* proj_w = (const float*)d_in[2];
    const float* proj_b = (const float*)d_in[3];
    float* out = (float*)d_out;                    // [256,4096] fp32

    char* B = (char*)d_ws;
    const size_t MB = 1u << 20;
    unsigned short* ao = (unsigned short*)(B);
    unsigned short* qm = (unsigned short*)(B + 2 * MB);
    unsigned short* km = (unsigned short*)(B + 4 * MB);
    unsigned short* vt = (unsigned short*)(B + 6 * MB);

    k_qkv<<<dim3(64, 12), 256, 0, stream>>>(x, qkv_w, qm, km, vt);
    k_attn<<<dim3(128, 8), 128, 0, stream>>>(qm, km, vt, ao);
    k_proj<<<dim3(64, 4), 256, 0, stream>>>(ao, proj_w, proj_b, out);
}

// Round 10
// 150.720 us; speedup vs baseline: 1.0839x; 1.0238x over previous
//
#include <hip/hip_runtime.h>
#include <hip/hip_bf16.h>

typedef __attribute__((ext_vector_type(8))) short short8;
typedef __attribute__((ext_vector_type(4))) float floatx4;

#define L2E 1.4426950408889634f

#if __has_builtin(__builtin_amdgcn_exp2f)
#define EXP2(x) __builtin_amdgcn_exp2f(x)
#else
#define EXP2(x) exp2f(x)
#endif
#if __has_builtin(__builtin_amdgcn_rcpf)
#define RCP(x) __builtin_amdgcn_rcpf(x)
#else
#define RCP(x) (1.0f / (x))
#endif

static __device__ __forceinline__ unsigned short f2bf(float f) {
    unsigned int u = __builtin_bit_cast(unsigned int, f);
    u += 0x7fffu + ((u >> 16) & 1u);   // RNE
    return (unsigned short)(u >> 16);
}
static __device__ __forceinline__ unsigned int pk_bf16(float a, float b) {
    __hip_bfloat162 h2 = __float22bfloat162_rn(make_float2(a, b));   // v_cvt_pk_bf16_f32
    unsigned int u;
    __builtin_memcpy(&u, &h2, 4);     // low16 = a, high16 = b
    return u;
}

// ---------------- 1) QKV GEMM ----------------
// R25: staging rewritten. Old: 128 scalar f2bf + 128 scalar ds_write_b16 per
// thread (m33 anti-pattern), V^T epilogue 16x 2B stores at 8KB stride (64-sector
// scatter/inst). New: per round, each thread loads 8 channels x 4 tokens as 8x
// float4 (256B contiguous per 16 lanes), packs with 16 pk_bf16, writes 4x
// ds_write_b128 (bank-uniform). V^T epilogue bounces the 64x64 tile through LDS
// (reusing At) then stores coalesced 128B segments. MFMA loop and q/k stores
// unchanged.
__global__ __launch_bounds__(256) void k_qkv(const float* __restrict__ x,
                                             const float* __restrict__ qw,
                                             unsigned short* __restrict__ qm,
                                             unsigned short* __restrict__ km,
                                             unsigned short* __restrict__ vt) {
    __shared__ __align__(16) unsigned short At[64][136];
    __shared__ __align__(16) unsigned short Wt[64][136];
    const int tid = threadIdx.x;
    const int wave = tid >> 6, lane = tid & 63;
    const int l16 = lane & 15, quad = lane >> 4;
    const int m0 = blockIdx.x * 64;
    const int o0 = blockIdx.y * 64;

    floatx4 acc[4] = {};
    for (int rnd = 0; rnd < 2; ++rnd) {
        const int cbase = rnd * 128;
        if (rnd) __syncthreads();
        {
            // x tile: channels cbase..cbase+127, tokens m0..m0+63.
            // thread: 8 channels x 4 tokens; At[tok][ch] = bf16(x[ch][tok]).
            const int tok0 = (tid & 15) * 4;
            const int c0   = (tid >> 4) * 8;
            const float* xp = x + (size_t)(cbase + c0) * 4096 + m0 + tok0;
            float4 v[8];
            #pragma unroll
            for (int j = 0; j < 8; ++j)
                v[j] = *reinterpret_cast<const float4*>(xp + (size_t)j * 4096);
            #pragma unroll
            for (int t = 0; t < 4; ++t) {
                unsigned int d[4];
                d[0] = pk_bf16((&v[0].x)[t], (&v[1].x)[t]);
                d[1] = pk_bf16((&v[2].x)[t], (&v[3].x)[t]);
                d[2] = pk_bf16((&v[4].x)[t], (&v[5].x)[t]);
                d[3] = pk_bf16((&v[6].x)[t], (&v[7].x)[t]);
                __builtin_memcpy(&At[tok0 + t][c0], d, 16);
            }
        }
        {
            const int o_l = tid >> 2, cp = (tid & 3) * 32;
            const float4* wp = reinterpret_cast<const float4*>(
                qw + (size_t)(o0 + o_l) * 256 + cbase + cp);
            #pragma unroll
            for (int j = 0; j < 2; ++j) {
                const float4 g0 = wp[4 * j + 0], g1 = wp[4 * j + 1];
                const float4 g2 = wp[4 * j + 2], g3 = wp[4 * j + 3];
                unsigned int u[8];
                u[0] = pk_bf16(g0.x, g0.y); u[1] = pk_bf16(g0.z, g0.w);
                u[2] = pk_bf16(g1.x, g1.y); u[3] = pk_bf16(g1.z, g1.w);
                u[4] = pk_bf16(g2.x, g2.y); u[5] = pk_bf16(g2.z, g2.w);
                u[6] = pk_bf16(g3.x, g3.y); u[7] = pk_bf16(g3.z, g3.w);
                __builtin_memcpy(&Wt[o_l][cp + 16 * j], u, 32);
            }
        }
        __syncthreads();
        #pragma unroll
        for (int cc = 0; cc < 4; ++cc) {
            const int c0 = cc * 32 + quad * 8;
            const short8 a = *reinterpret_cast<const short8*>(&At[wave * 16 + l16][c0]);
            #pragma unroll
            for (int t4 = 0; t4 < 4; ++t4) {
                const short8 b = *reinterpret_cast<const short8*>(&Wt[t4 * 16 + l16][c0]);
                acc[t4] = __builtin_amdgcn_mfma_f32_16x16x32_bf16(a, b, acc[t4], 0, 0, 0);
            }
        }
    }

    const int s = o0 >> 8;   // block-uniform: 0=q, 1=k, 2=v
    if (s < 2) {
        const float qscale = 0.17677669529663687f * L2E;
        #pragma unroll
        for (int t4 = 0; t4 < 4; ++t4) {
            #pragma unroll
            for (int r = 0; r < 4; ++r) {
                const int n = m0 + wave * 16 + quad * 4 + r;
                const int o = o0 + t4 * 16 + l16;
                const int rem = o & 255, head = rem >> 5, t = rem & 31;
                if (s == 0)  qm[((size_t)head * 4096 + n) * 32 + t] = f2bf(acc[t4][r] * qscale);
                else         km[((size_t)head * 4096 + n) * 32 + t] = f2bf(acc[t4][r]);
            }
        }
    } else {
        // V^T: bounce through LDS (reuse At) then coalesced stores.
        __syncthreads();   // all waves done reading At/Wt
        unsigned short (*Ct)[72] = reinterpret_cast<unsigned short(*)[72]>(&At[0][0]);
        #pragma unroll
        for (int t4 = 0; t4 < 4; ++t4) {
            unsigned int d2[2];
            d2[0] = pk_bf16(acc[t4][0], acc[t4][1]);
            d2[1] = pk_bf16(acc[t4][2], acc[t4][3]);
            __builtin_memcpy(&Ct[t4 * 16 + l16][wave * 16 + quad * 4], d2, 8);
        }
        __syncthreads();
        const int row = tid >> 2, col0 = (tid & 3) * 16;
        unsigned short* dst = vt + (size_t)(o0 - 512 + row) * 4096 + m0 + col0;
        const short8 ca = *reinterpret_cast<const short8*>(&Ct[row][col0]);
        const short8 cb = *reinterpret_cast<const short8*>(&Ct[row][col0 + 8]);
        *reinterpret_cast<short8*>(dst) = ca;
        *reinterpret_cast<short8*>(dst + 8) = cb;
    }
}

// ---------------- 2) flash attention: R19 verbatim (best measured: 74.9us) ----------------
// LDS-shared K/V tiles, 2-phase double buffer, PT plain layout. R20-R24 variants
// (permlane, bpermute, PT swizzle, 2-slot phases, 2-wave blocks) all regressed;
// this is the empirical optimum of the family.
__global__ __launch_bounds__(256, 2) void k_attn(const unsigned short* __restrict__ qm,
                                                 const unsigned short* __restrict__ km,
                                                 const unsigned short* __restrict__ vt,
                                                 unsigned short* __restrict__ ao) {
    const int h   = blockIdx.y;
    const int nq0 = blockIdx.x * 64;          // 64 q-rows per block (same dq for all)
    const int tid = threadIdx.x;
    const int wv  = tid >> 6;                 // wave owns q-tile nq0 + wv*16
    const int lane = tid & 63;
    const int l16 = lane & 15, quad = lane >> 4;
    const int nqw = nq0 + wv * 16;

    __shared__ __align__(16) unsigned short Kt[2][2048];   // [buf][key*32+dim ^ swz]
    __shared__ __align__(16) unsigned short Vt[2][2048];   // [buf][kg*256+dim*8 ^ swz]
    __shared__ __align__(16) unsigned short PT[4][16][72]; // per-wave P^T scratch

    const short8 a_q = *reinterpret_cast<const short8*>(
        qm + ((size_t)h * 4096 + nqw + l16) * 32 + quad * 8);

    const int hq = (nqw >> 4) & 15;
    const int dq = nq0 >> 8;
    float dw2[4];
    #pragma unroll
    for (int r = 0; r < 4; ++r) {
        const float dw = (float)(quad * 4 + r - l16);
        dw2[r] = dw * dw;
    }

    const int dk_lo = (dq > 9) ? dq - 9 : 0;
    const int dk_hi = (dq < 6) ? dq + 9 : 15;
    const int NT = 4 * (dk_hi - dk_lo + 1);

    const int skey = tid >> 2;
    const int sdo  = (tid & 3) * 8;
    const int sdim = tid >> 3;
    const int skg  = tid & 7;
    const unsigned short* ksrc = km + ((size_t)h << 17) + skey * 32 + sdo;
    const unsigned short* vsrc = vt + (((size_t)h * 32 + sdim) << 12) + skg * 8;
    const int kdst = (skey * 32 + sdo) ^ ((skey & 7) << 3);
    const int vdst = (skg * 256 + sdim * 8) ^ (skg << 3);

    float l_acc = 0.f;
    floatx4 o_acc[2] = {};

#define J0T(T) (((dk_lo + ((T) >> 2)) << 8) + (((T) & 3) << 6))

    short8 gK, gV;
    {
        const int j0 = J0T(0);
        gK = *reinterpret_cast<const short8*>(ksrc + (size_t)j0 * 32);
        gV = *reinterpret_cast<const short8*>(vsrc + j0);
        *reinterpret_cast<short8*>(&Kt[0][kdst]) = gK;
        *reinterpret_cast<short8*>(&Vt[0][vdst]) = gV;
        const int j1 = J0T(1);
        gK = *reinterpret_cast<const short8*>(ksrc + (size_t)j1 * 32);
        gV = *reinterpret_cast<const short8*>(vsrc + j1);
    }
    __syncthreads();

    for (int t = 0; t < NT; ++t) {
        const int cb = t & 1, nb = cb ^ 1;

        *reinterpret_cast<short8*>(&Kt[nb][kdst]) = gK;
        *reinterpret_cast<short8*>(&Vt[nb][vdst]) = gV;

        {
            const int tn = (t + 2 < NT) ? t + 2 : NT - 1;
            const int j2 = J0T(tn);
            gK = *reinterpret_cast<const short8*>(ksrc + (size_t)j2 * 32);
            gV = *reinterpret_cast<const short8*>(vsrc + j2);
        }

        {
            const int dk = dk_lo + (t >> 2), g = t & 3;
            const int dd = dq - dk;
            const int bb = 100 - dd * dd;
            const int h0 = hq - 4 * g;
            int thr[4];
            thr[0] = bb - h0 * h0;
            thr[1] = bb - (h0 - 1) * (h0 - 1);
            thr[2] = bb - (h0 - 2) * (h0 - 2);
            thr[3] = bb - (h0 - 3) * (h0 - 3);

            if (thr[0] > 0 || thr[1] > 0 || thr[2] > 0 || thr[3] > 0) {
                #pragma unroll
                for (int t4 = 0; t4 < 4; ++t4) {
                    const bool sib = (thr[t4 ^ 1] > 0);
                    if (thr[t4] > 0) {
                        const short8 kf = *reinterpret_cast<const short8*>(
                            &Kt[cb][((t4 * 16 + l16) * 32 + quad * 8) ^ ((l16 & 7) << 3)]);
                        const floatx4 sf = __builtin_amdgcn_mfma_f32_16x16x32_bf16(
                            kf, a_q, (floatx4){0.f, 0.f, 0.f, 0.f}, 0, 0, 0);
                        const float thrf = (float)thr[t4];
                        const float p0 = (dw2[0] < thrf) ? EXP2(sf[0]) : 0.f;
                        const float p1 = (dw2[1] < thrf) ? EXP2(sf[1]) : 0.f;
                        const float p2 = (dw2[2] < thrf) ? EXP2(sf[2]) : 0.f;
                        const float p3 = (dw2[3] < thrf) ? EXP2(sf[3]) : 0.f;
                        l_acc += (p0 + p1) + (p2 + p3);
                        unsigned int pair[2];
                        pair[0] = pk_bf16(p0, p1);
                        pair[1] = pk_bf16(p2, p3);
                        __builtin_memcpy(&PT[wv][l16][t4 * 16 + quad * 4], pair, 8);
                    } else if (sib) {
                        const unsigned int zz[2] = {0u, 0u};
                        __builtin_memcpy(&PT[wv][l16][t4 * 16 + quad * 4], zz, 8);
                    }
                }
                #pragma unroll
                for (int kt = 0; kt < 2; ++kt) {
                    if (thr[2 * kt] > 0 || thr[2 * kt + 1] > 0) {
                        const short8 b_p = *reinterpret_cast<const short8*>(
                            &PT[wv][l16][kt * 32 + quad * 8]);
                        const int kg = kt * 4 + quad;
                        #pragma unroll
                        for (int hf = 0; hf < 2; ++hf) {
                            const short8 vf = *reinterpret_cast<const short8*>(
                                &Vt[cb][(kg * 256 + (hf * 16 + l16) * 8) ^ (kg << 3)]);
                            o_acc[hf] = __builtin_amdgcn_mfma_f32_16x16x32_bf16(
                                vf, b_p, o_acc[hf], 0, 0, 0);
                        }
                    }
                }
            }
        }
        __syncthreads();
    }
#undef J0T

    l_acc += __shfl_xor(l_acc, 16);
    l_acc += __shfl_xor(l_acc, 32);
    const float inv = RCP(l_acc);
    #pragma unroll
    for (int hf = 0; hf < 2; ++hf) {
        unsigned int uu[2];
        uu[0] = pk_bf16(o_acc[hf][0] * inv, o_acc[hf][1] * inv);
        uu[1] = pk_bf16(o_acc[hf][2] * inv, o_acc[hf][3] * inv);
        __builtin_memcpy(ao + (size_t)(nqw + l16) * 256 + h * 32 + hf * 16 + quad * 4,
                         uu, 8);
    }
}

// ---------------- 3) proj GEMM + bias ----------------
// R25: n-tile 64 -> 32: grid 256 -> 512 blocks = 2 blocks/CU (was exactly 1/CU,
// zero TLP to hide the K-loop's global-load latency). Per-block MFMA halves;
// Pt staging unchanged.
__global__ __launch_bounds__(256) void k_proj(const unsigned short* __restrict__ ao,
                                              const float* __restrict__ pw,
                                              const float* __restrict__ pb,
                                              float* __restrict__ out) {
    __shared__ __align__(16) unsigned short Pt[64][264];
    const int tid = threadIdx.x;
    const int wave = tid >> 6, lane = tid & 63;
    const int l16 = lane & 15, quad = lane >> 4;
    const int n0 = blockIdx.x * 32;
    const int m0 = blockIdx.y * 64;

    {
        const int o_l = tid >> 2, cp = (tid & 3) * 64;
        const float4* wp = reinterpret_cast<const float4*>(pw + (size_t)(m0 + o_l) * 256 + cp);
        #pragma unroll
        for (int j = 0; j < 4; ++j) {
            const float4 g0 = wp[4 * j + 0], g1 = wp[4 * j + 1];
            const float4 g2 = wp[4 * j + 2], g3 = wp[4 * j + 3];
            unsigned int u[8];
            u[0] = pk_bf16(g0.x, g0.y); u[1] = pk_bf16(g0.z, g0.w);
            u[2] = pk_bf16(g1.x, g1.y); u[3] = pk_bf16(g1.z, g1.w);
            u[4] = pk_bf16(g2.x, g2.y); u[5] = pk_bf16(g2.z, g2.w);
            u[6] = pk_bf16(g3.x, g3.y); u[7] = pk_bf16(g3.z, g3.w);
            __builtin_memcpy(&Pt[o_l][cp + 16 * j], u, 32);
        }
    }
    __syncthreads();

    floatx4 acc[2] = {};
    #pragma unroll
    for (int cc = 0; cc < 8; ++cc) {
        const int c0 = cc * 32 + quad * 8;
        const short8 a = *reinterpret_cast<const short8*>(&Pt[wave * 16 + l16][c0]);
        #pragma unroll
        for (int t4 = 0; t4 < 2; ++t4) {
            const short8 b = *reinterpret_cast<const short8*>(
                ao + (size_t)(n0 + t4 * 16 + l16) * 256 + c0);
            acc[t4] = __builtin_amdgcn_mfma_f32_16x16x32_bf16(a, b, acc[t4], 0, 0, 0);
        }
    }
    #pragma unroll
    for (int t4 = 0; t4 < 2; ++t4) {
        #pragma unroll
        for (int r = 0; r < 4; ++r) {
            const int o = m0 + wave * 16 + quad * 4 + r;
            const int n = n0 + t4 * 16 + l16;
            out[(size_t)o * 4096 + n] = acc[t4][r] + pb[o];
        }
    }
}

extern "C" void kernel_launch(void* const* d_in, const int* in_sizes, int n_in,
                              void* d_out, int out_size, void* d_ws, size_t ws_size,
                              hipStream_t stream) {
    const float* x      = (const float*)d_in[0];
    const float* qkv_w  = (const float*)d_in[1];
    const float* proj_w = (const float*)d_in[2];
    const float* proj_b = (const float*)d_in[3];
    float* out = (float*)d_out;                    // [256,4096] fp32

    char* B = (char*)d_ws;
    const size_t MB = 1u << 20;
    unsigned short* ao = (unsigned short*)(B);
    unsigned short* qm = (unsigned short*)(B + 2 * MB);
    unsigned short* km = (unsigned short*)(B + 4 * MB);
    unsigned short* vt = (unsigned short*)(B + 6 * MB);

    k_qkv<<<dim3(64, 12), 256, 0, stream>>>(x, qkv_w, qm, km, vt);
    k_attn<<<dim3(64, 8), 256, 0, stream>>>(qm, km, vt, ao);
    k_proj<<<dim3(128, 4), 256, 0, stream>>>(ao, proj_w, proj_b, out);
}

// Round 13
// 136.420 us; speedup vs baseline: 1.1975x; 1.1048x over previous
//
#include <hip/hip_runtime.h>
#include <hip/hip_bf16.h>

typedef __attribute__((ext_vector_type(8))) short short8;
typedef __attribute__((ext_vector_type(4))) float floatx4;

#define L2E 1.4426950408889634f

#if __has_builtin(__builtin_amdgcn_exp2f)
#define EXP2(x) __builtin_amdgcn_exp2f(x)
#else
#define EXP2(x) exp2f(x)
#endif
#if __has_builtin(__builtin_amdgcn_rcpf)
#define RCP(x) __builtin_amdgcn_rcpf(x)
#else
#define RCP(x) (1.0f / (x))
#endif

static __device__ __forceinline__ unsigned short f2bf(float f) {
    unsigned int u = __builtin_bit_cast(unsigned int, f);
    u += 0x7fffu + ((u >> 16) & 1u);   // RNE
    return (unsigned short)(u >> 16);
}
static __device__ __forceinline__ unsigned int pk_bf16(float a, float b) {
    __hip_bfloat162 h2 = __float22bfloat162_rn(make_float2(a, b));   // v_cvt_pk_bf16_f32
    unsigned int u;
    __builtin_memcpy(&u, &h2, 4);     // low16 = a, high16 = b
    return u;
}

// ---------------- 1) QKV GEMM (R25 verbatim: vectorized staging, LDS-bounced V^T) ----------------
__global__ __launch_bounds__(256) void k_qkv(const float* __restrict__ x,
                                             const float* __restrict__ qw,
                                             unsigned short* __restrict__ qm,
                                             unsigned short* __restrict__ km,
                                             unsigned short* __restrict__ vt) {
    __shared__ __align__(16) unsigned short At[64][136];
    __shared__ __align__(16) unsigned short Wt[64][136];
    const int tid = threadIdx.x;
    const int wave = tid >> 6, lane = tid & 63;
    const int l16 = lane & 15, quad = lane >> 4;
    const int m0 = blockIdx.x * 64;
    const int o0 = blockIdx.y * 64;

    floatx4 acc[4] = {};
    for (int rnd = 0; rnd < 2; ++rnd) {
        const int cbase = rnd * 128;
        if (rnd) __syncthreads();
        {
            const int tok0 = (tid & 15) * 4;
            const int c0   = (tid >> 4) * 8;
            const float* xp = x + (size_t)(cbase + c0) * 4096 + m0 + tok0;
            float4 v[8];
            #pragma unroll
            for (int j = 0; j < 8; ++j)
                v[j] = *reinterpret_cast<const float4*>(xp + (size_t)j * 4096);
            #pragma unroll
            for (int t = 0; t < 4; ++t) {
                unsigned int d[4];
                d[0] = pk_bf16((&v[0].x)[t], (&v[1].x)[t]);
                d[1] = pk_bf16((&v[2].x)[t], (&v[3].x)[t]);
                d[2] = pk_bf16((&v[4].x)[t], (&v[5].x)[t]);
                d[3] = pk_bf16((&v[6].x)[t], (&v[7].x)[t]);
                __builtin_memcpy(&At[tok0 + t][c0], d, 16);
            }
        }
        {
            const int o_l = tid >> 2, cp = (tid & 3) * 32;
            const float4* wp = reinterpret_cast<const float4*>(
                qw + (size_t)(o0 + o_l) * 256 + cbase + cp);
            #pragma unroll
            for (int j = 0; j < 2; ++j) {
                const float4 g0 = wp[4 * j + 0], g1 = wp[4 * j + 1];
                const float4 g2 = wp[4 * j + 2], g3 = wp[4 * j + 3];
                unsigned int u[8];
                u[0] = pk_bf16(g0.x, g0.y); u[1] = pk_bf16(g0.z, g0.w);
                u[2] = pk_bf16(g1.x, g1.y); u[3] = pk_bf16(g1.z, g1.w);
                u[4] = pk_bf16(g2.x, g2.y); u[5] = pk_bf16(g2.z, g2.w);
                u[6] = pk_bf16(g3.x, g3.y); u[7] = pk_bf16(g3.z, g3.w);
                __builtin_memcpy(&Wt[o_l][cp + 16 * j], u, 32);
            }
        }
        __syncthreads();
        #pragma unroll
        for (int cc = 0; cc < 4; ++cc) {
            const int c0 = cc * 32 + quad * 8;
            const short8 a = *reinterpret_cast<const short8*>(&At[wave * 16 + l16][c0]);
            #pragma unroll
            for (int t4 = 0; t4 < 4; ++t4) {
                const short8 b = *reinterpret_cast<const short8*>(&Wt[t4 * 16 + l16][c0]);
                acc[t4] = __builtin_amdgcn_mfma_f32_16x16x32_bf16(a, b, acc[t4], 0, 0, 0);
            }
        }
    }

    const int s = o0 >> 8;   // block-uniform: 0=q, 1=k, 2=v
    if (s < 2) {
        const float qscale = 0.17677669529663687f * L2E;
        #pragma unroll
        for (int t4 = 0; t4 < 4; ++t4) {
            #pragma unroll
            for (int r = 0; r < 4; ++r) {
                const int n = m0 + wave * 16 + quad * 4 + r;
                const int o = o0 + t4 * 16 + l16;
                const int rem = o & 255, head = rem >> 5, t = rem & 31;
                if (s == 0)  qm[((size_t)head * 4096 + n) * 32 + t] = f2bf(acc[t4][r] * qscale);
                else         km[((size_t)head * 4096 + n) * 32 + t] = f2bf(acc[t4][r]);
            }
        }
    } else {
        __syncthreads();
        unsigned short (*Ct)[72] = reinterpret_cast<unsigned short(*)[72]>(&At[0][0]);
        #pragma unroll
        for (int t4 = 0; t4 < 4; ++t4) {
            unsigned int d2[2];
            d2[0] = pk_bf16(acc[t4][0], acc[t4][1]);
            d2[1] = pk_bf16(acc[t4][2], acc[t4][3]);
            __builtin_memcpy(&Ct[t4 * 16 + l16][wave * 16 + quad * 4], d2, 8);
        }
        __syncthreads();
        const int row = tid >> 2, col0 = (tid & 3) * 16;
        unsigned short* dst = vt + (size_t)(o0 - 512 + row) * 4096 + m0 + col0;
        const short8 ca = *reinterpret_cast<const short8*>(&Ct[row][col0]);
        const short8 cb = *reinterpret_cast<const short8*>(&Ct[row][col0 + 8]);
        *reinterpret_cast<short8*>(dst) = ca;
        *reinterpret_cast<short8*>(dst + 8) = cb;
    }
}

// ---------------- 2) flash attention: 2 branch-free tile chains per barrier-phase ----------------
// R28: R26/R27 cooperative fusion abandoned (deterministic fence-insensitive failure
// + graph-capture replay produces zeros). This round re-runs R23's 2-tiles-per-phase
// with both of its identified defects fixed:
//  (a) PT back to the PLAIN stride-72 layout -- bank math shows its b128 read is
//      exactly at the uniform 8-lanes/4-bank-group floor; R23's "swizzle" made one
//      group take 16/64 lanes (13.9M conflicts, +17us).
//  (b) chains made BRANCH-FREE (R18 scheme: dead subtiles produce exact P=0 via the
//      dw2<thr cndmask) so the phase is one straight-line block:
//      SSTAGE(A); SSTAGE(B); PV(A); PV(B) -- B's LDS-read latency hides under A's
//      MFMA/exp, A's PT write->read gap hides under B's chain. R23's comp() lambdas
//      had wave-uniform early-out BRANCHES between chains, blocking interleave.
// Heavy blocks: 64 -> 32 barrier phases. Per-slot o_acc avoids MFMA acc-dependency
// serialization between the two PV groups. LDS 50KB, 2 blocks/CU.
__global__ __launch_bounds__(256, 2) void k_attn(const unsigned short* __restrict__ qm,
                                                 const unsigned short* __restrict__ km,
                                                 const unsigned short* __restrict__ vt,
                                                 unsigned short* __restrict__ ao) {
    const int h   = blockIdx.y;
    const int nq0 = blockIdx.x * 64;          // 64 q-rows per block (same dq for all)
    const int tid = threadIdx.x;
    const int wv  = tid >> 6;                 // wave owns q-tile nq0 + wv*16
    const int lane = tid & 63;
    const int l16 = lane & 15, quad = lane >> 4;
    const int nqw = nq0 + wv * 16;

    __shared__ __align__(16) unsigned short Kt[2][2][2048];   // [buf][slot][key*32+dim ^ swz]
    __shared__ __align__(16) unsigned short Vt[2][2][2048];   // [buf][slot][kg*256+dim*8 ^ swz]
    __shared__ __align__(16) unsigned short PT[4][2][16][72]; // [wave][slot][q][key] plain

    const short8 a_q = *reinterpret_cast<const short8*>(
        qm + ((size_t)h * 4096 + nqw + l16) * 32 + quad * 8);

    const int hq = (nqw >> 4) & 15;
    const int dq = nq0 >> 8;
    float dw2[4];
    #pragma unroll
    for (int r = 0; r < 4; ++r) {
        const float dw = (float)(quad * 4 + r - l16);
        dw2[r] = dw * dw;
    }

    const int dk_lo = (dq > 9) ? dq - 9 : 0;
    const int dk_hi = (dq < 6) ? dq + 9 : 15;
    const int NT = 4 * (dk_hi - dk_lo + 1);   // 40..64, even

    const int skey = tid >> 2;
    const int sdo  = (tid & 3) * 8;
    const int sdim = tid >> 3;
    const int skg  = tid & 7;
    const unsigned short* ksrc = km + ((size_t)h << 17) + skey * 32 + sdo;
    const unsigned short* vsrc = vt + (((size_t)h * 32 + sdim) << 12) + skg * 8;
    const int kdst = (skey * 32 + sdo) ^ ((skey & 7) << 3);
    const int vdst = (skg * 256 + sdim * 8) ^ (skg << 3);

    float l_acc = 0.f;
    floatx4 o_acc[2][2] = {};                 // [slot][hf]

#define J0T(T) (((dk_lo + ((T) >> 2)) << 8) + (((T) & 3) << 6))

    short8 rK[2], rV[2];
#define LOAD2(TA, TB) {                                                   \
        const int ja_ = J0T(TA), jb_ = J0T(TB);                           \
        rK[0] = *reinterpret_cast<const short8*>(ksrc + (size_t)ja_ * 32);\
        rV[0] = *reinterpret_cast<const short8*>(vsrc + ja_);             \
        rK[1] = *reinterpret_cast<const short8*>(ksrc + (size_t)jb_ * 32);\
        rV[1] = *reinterpret_cast<const short8*>(vsrc + jb_);             \
    }
#define WRITE2(NB) {                                                      \
        *reinterpret_cast<short8*>(&Kt[NB][0][kdst]) = rK[0];             \
        *reinterpret_cast<short8*>(&Vt[NB][0][vdst]) = rV[0];             \
        *reinterpret_cast<short8*>(&Kt[NB][1][kdst]) = rK[1];             \
        *reinterpret_cast<short8*>(&Vt[NB][1][vdst]) = rV[1];             \
    }

// branch-free S stage: every subtile computes; dead ones give exact P=0 (cndmask)
#define SSTAGE(T, CB, SL) {                                               \
        const int dk_ = dk_lo + ((T) >> 2), g_ = (T) & 3;                 \
        const int dd_ = dq - dk_;                                         \
        const int bb_ = 100 - dd_ * dd_;                                  \
        const int h0_ = hq - 4 * g_;                                      \
        int th_[4];                                                       \
        th_[0] = bb_ - h0_ * h0_;                                         \
        th_[1] = bb_ - (h0_ - 1) * (h0_ - 1);                             \
        th_[2] = bb_ - (h0_ - 2) * (h0_ - 2);                             \
        th_[3] = bb_ - (h0_ - 3) * (h0_ - 3);                             \
        _Pragma("unroll")                                                 \
        for (int t4 = 0; t4 < 4; ++t4) {                                  \
            const short8 kf = *reinterpret_cast<const short8*>(           \
                &Kt[CB][SL][((t4 * 16 + l16) * 32 + quad * 8) ^ ((l16 & 7) << 3)]); \
            const floatx4 sf = __builtin_amdgcn_mfma_f32_16x16x32_bf16(   \
                kf, a_q, (floatx4){0.f, 0.f, 0.f, 0.f}, 0, 0, 0);         \
            const float thrf = (float)th_[t4];                            \
            const float p0 = (dw2[0] < thrf) ? EXP2(sf[0]) : 0.f;         \
            const float p1 = (dw2[1] < thrf) ? EXP2(sf[1]) : 0.f;         \
            const float p2 = (dw2[2] < thrf) ? EXP2(sf[2]) : 0.f;         \
            const float p3 = (dw2[3] < thrf) ? EXP2(sf[3]) : 0.f;         \
            l_acc += (p0 + p1) + (p2 + p3);                               \
            unsigned int pair_[2];                                        \
            pair_[0] = pk_bf16(p0, p1);                                   \
            pair_[1] = pk_bf16(p2, p3);                                   \
            __builtin_memcpy(&PT[wv][SL][l16][t4 * 16 + quad * 4], pair_, 8); \
        }                                                                 \
    }

#define PVST(CB, SL) {                                                    \
        _Pragma("unroll")                                                 \
        for (int kt = 0; kt < 2; ++kt) {                                  \
            const short8 b_p = *reinterpret_cast<const short8*>(          \
                &PT[wv][SL][l16][kt * 32 + quad * 8]);                    \
            const int kg = kt * 4 + quad;                                 \
            _Pragma("unroll")                                             \
            for (int hf = 0; hf < 2; ++hf) {                              \
                const short8 vf = *reinterpret_cast<const short8*>(       \
                    &Vt[CB][SL][(kg * 256 + (hf * 16 + l16) * 8) ^ (kg << 3)]); \
                o_acc[SL][hf] = __builtin_amdgcn_mfma_f32_16x16x32_bf16(  \
                    vf, b_p, o_acc[SL][hf], 0, 0, 0);                     \
            }                                                             \
        }                                                                 \
    }

    // prologue: tiles 0,1 -> buf0; tiles 2,3 -> regs
    LOAD2(0, 1)
    WRITE2(0)
    LOAD2(2, 3)
    __syncthreads();

    for (int t2 = 0; t2 < NT; t2 += 2) {
        const int cb = (t2 >> 1) & 1, nb = cb ^ 1;
        WRITE2(nb)                      // tiles t2+2, t2+3 (vmcnt waits here)
        {
            int ta = t2 + 4; if (ta >= NT) ta = NT - 1;
            int tb = t2 + 5; if (tb >= NT) tb = NT - 1;
            LOAD2(ta, tb)               // issue early; consumed next phase
        }
        SSTAGE(t2,     cb, 0)           // straight-line: two independent chains
        SSTAGE(t2 + 1, cb, 1)
        PVST(cb, 0)
        PVST(cb, 1)
        __syncthreads();
    }
#undef PVST
#undef SSTAGE
#undef WRITE2
#undef LOAD2
#undef J0T

    // epilogue: waves own disjoint q-rows; direct write
    l_acc += __shfl_xor(l_acc, 16);
    l_acc += __shfl_xor(l_acc, 32);
    const float inv = RCP(l_acc);
    #pragma unroll
    for (int hf = 0; hf < 2; ++hf) {
        const floatx4 os = o_acc[0][hf] + o_acc[1][hf];
        unsigned int uu[2];
        uu[0] = pk_bf16(os[0] * inv, os[1] * inv);
        uu[1] = pk_bf16(os[2] * inv, os[3] * inv);
        __builtin_memcpy(ao + (size_t)(nqw + l16) * 256 + h * 32 + hf * 16 + quad * 4,
                         uu, 8);
    }
}

// ---------------- 3) proj GEMM + bias (R25 verbatim: 32-wide n-tiles, 2 blocks/CU) ----------------
__global__ __launch_bounds__(256) void k_proj(const unsigned short* __restrict__ ao,
                                              const float* __restrict__ pw,
                                              const float* __restrict__ pb,
                                              float* __restrict__ out) {
    __shared__ __align__(16) unsigned short Pt[64][264];
    const int tid = threadIdx.x;
    const int wave = tid >> 6, lane = tid & 63;
    const int l16 = lane & 15, quad = lane >> 4;
    const int n0 = blockIdx.x * 32;
    const int m0 = blockIdx.y * 64;

    {
        const int o_l = tid >> 2, cp = (tid & 3) * 64;
        const float4* wp = reinterpret_cast<const float4*>(pw + (size_t)(m0 + o_l) * 256 + cp);
        #pragma unroll
        for (int j = 0; j < 4; ++j) {
            const float4 g0 = wp[4 * j + 0], g1 = wp[4 * j + 1];
            const float4 g2 = wp[4 * j + 2], g3 = wp[4 * j + 3];
            unsigned int u[8];
            u[0] = pk_bf16(g0.x, g0.y); u[1] = pk_bf16(g0.z, g0.w);
            u[2] = pk_bf16(g1.x, g1.y); u[3] = pk_bf16(g1.z, g1.w);
            u[4] = pk_bf16(g2.x, g2.y); u[5] = pk_bf16(g2.z, g2.w);
            u[6] = pk_bf16(g3.x, g3.y); u[7] = pk_bf16(g3.z, g3.w);
            __builtin_memcpy(&Pt[o_l][cp + 16 * j], u, 32);
        }
    }
    __syncthreads();

    floatx4 acc[2] = {};
    #pragma unroll
    for (int cc = 0; cc < 8; ++cc) {
        const int c0 = cc * 32 + quad * 8;
        const short8 a = *reinterpret_cast<const short8*>(&Pt[wave * 16 + l16][c0]);
        #pragma unroll
        for (int t4 = 0; t4 < 2; ++t4) {
            const short8 b = *reinterpret_cast<const short8*>(
                ao + (size_t)(n0 + t4 * 16 + l16) * 256 + c0);
            acc[t4] = __builtin_amdgcn_mfma_f32_16x16x32_bf16(a, b, acc[t4], 0, 0, 0);
        }
    }
    #pragma unroll
    for (int t4 = 0; t4 < 2; ++t4) {
        #pragma unroll
        for (int r = 0; r < 4; ++r) {
            const int o = m0 + wave * 16 + quad * 4 + r;
            const int n = n0 + t4 * 16 + l16;
            out[(size_t)o * 4096 + n] = acc[t4][r] + pb[o];
        }
    }
}

extern "C" void kernel_launch(void* const* d_in, const int* in_sizes, int n_in,
                              void* d_out, int out_size, void* d_ws, size_t ws_size,
                              hipStream_t stream) {
    const float* x      = (const float*)d_in[0];
    const float* qkv_w  = (const float*)d_in[1];
    const float* proj_w = (const float*)d_in[2];
    const float* proj_b = (const float*)d_in[3];
    float* out = (float*)d_out;                    // [256,4096] fp32

    char* B = (char*)d_ws;
    const size_t MB = 1u << 20;
    unsigned short* ao = (unsigned short*)(B);
    unsigned short* qm = (unsigned short*)(B + 2 * MB);
    unsigned short* km = (unsigned short*)(B + 4 * MB);
    unsigned short* vt = (unsigned short*)(B + 6 * MB);

    k_qkv<<<dim3(64, 12), 256, 0, stream>>>(x, qkv_w, qm, km, vt);
    k_attn<<<dim3(64, 8), 256, 0, stream>>>(qm, km, vt, ao);
    k_proj<<<dim3(128, 4), 256, 0, stream>>>(ao, proj_w, proj_b, out);
}